// Round 8
// baseline (377.816 us; speedup 1.0000x reference)
//
#include <hip/hip_runtime.h>
#include <hip/hip_bf16.h>

// EdgeDetourHead: B=2, N=512, E=128, H=256
// R14: persistent pipeline with an EXACT register budget.
// R9/R12/R13 all died of spill, not of the pipeline idea. Fixes vs R13:
//  (a) w1c NOT register-cached (streamed from L2, R8-proven)  [-32 reg]
//  (b) no global_load_lds w2 staging (plain frag streams)      [-risk]
//  (c) ONE f32x16 C[4] array reused for L1-acc and L2-acc      [-64 reg]
// Peak ~ jr(32)+hn(32)+C(64)+working ~ 170 <= 256 @ launch_bounds(512,2).
// Structure: 8 waves x 1 m-tile, TJ=128, persistent over NI=16 i at fixed
// (jt,b) -> 256 WGs = 1/CU. LDS: D(34.8K) + h1(67.6K) + pp(4K) = 104K.
// 2 __syncthreads()/iter: B1 {h1 ready}, B2 {pp + D[next] ready}.
// Loop-invariant: j-rows in regs (once); PBT/w2/w1c addrs L2-hot.
// Per-iter new traffic: 1 i-row (512B) + 1 euclid row (2KB) + PA row.
// Tripwire: WRITE_SIZE >> 2MB = spill = round void.

#define BN 512
#define EE 128
#define HH 256
#define NI 16            // i-rows per persistent WG

typedef __attribute__((ext_vector_type(8)))  short short8;
typedef __attribute__((ext_vector_type(4)))  short short4v;
typedef __attribute__((ext_vector_type(16))) float f32x16;
typedef __attribute__((ext_vector_type(4)))  float f32x4;

static __device__ __forceinline__ unsigned short f2bf(float f) {
    __bf16 h = (__bf16)f;
    return __builtin_bit_cast(unsigned short, h);
}
static __device__ __forceinline__ f32x16 zero16() {
    f32x16 v;
    #pragma unroll
    for (int i = 0; i < 16; ++i) v[i] = 0.f;
    return v;
}
#define MFMA(a, b, c) __builtin_amdgcn_mfma_f32_32x32x16_bf16((a), (b), (c), 0, 0, 0)

// ---------------- kernel 0: prep (R10/R11-proven) ----------------
// blocks 0..255: weight pack. Packed frag idx = ((kb*8 + mtile)*64 + l)*8 + t ;
//   value W[kb*16+(l>>5)*8+t][mtile*32+(l&31)]  == A-frag of W^T.
// blocks 256..511: PA[b,i,f] = h_i@W1a + b1 (fp32, row-major) and
//   PBT[b][f>>2][j][f&3] = (h_j@W1b)[f] (fp32, transposed). 4 nodes per block.
__global__ void prep(const float* __restrict__ node, const float* __restrict__ W1,
                     const float* __restrict__ W2, const float* __restrict__ b1,
                     float* __restrict__ PA, float* __restrict__ PBT,
                     unsigned short* __restrict__ w1c_p, unsigned short* __restrict__ w2_p) {
    int blk = blockIdx.x;
    if (blk < 256) {
        int idx = blk * 256 + threadIdx.x;             // 0..65535
        int t = idx & 7, l = (idx >> 3) & 63, mt = (idx >> 9) & 7, kb = idx >> 12;
        int k = kb * 16 + (l >> 5) * 8 + t, m = mt * 32 + (l & 31);
        w2_p[idx] = f2bf(W2[k * HH + m]);              // W2^T A-frags: kb 0..15
        if (idx < 32768)                               // W1c^T: kb 0..7
            w1c_p[idx] = f2bf(W1[(2 * EE + k) * HH + m]);
    } else {
        int bi0 = (blk - 256) * 4;                     // 4 nodes per block
        int h = threadIdx.x;
        float sa[4], sb[4];
        #pragma unroll
        for (int n = 0; n < 4; ++n) { sa[n] = b1[h]; sb[n] = 0.f; }
        #pragma unroll 8
        for (int e = 0; e < EE; ++e) {
            float wa = W1[e * HH + h];
            float wb = W1[(EE + e) * HH + h];
            #pragma unroll
            for (int n = 0; n < 4; ++n) {
                float nv = node[(size_t)(bi0 + n) * EE + e];   // wave-uniform
                sa[n] += nv * wa;
                sb[n] += nv * wb;
            }
        }
        #pragma unroll
        for (int n = 0; n < 4; ++n) {
            int bi = bi0 + n;
            PA[(size_t)bi * HH + h] = sa[n];
            PBT[(((size_t)(bi >> 9) * 64 + (h >> 2)) * BN + (bi & 511)) * 4 + (h & 3)] = sb[n];
        }
    }
}

// ---------------- kernel 1: fused main, persistent over NI i-rows ----------------
// 8 waves; wave owns ONE 32-feat m-tile x all 4 pair n-tiles (128 pairs).
__global__ __launch_bounds__(512, 2) void edge_main(
    const float* __restrict__ node, const float* __restrict__ euclid,
    const float* __restrict__ W1, const float* __restrict__ W3,
    const float* __restrict__ b3, const float* __restrict__ b2v,
    const float* __restrict__ PA, const float* __restrict__ PBT,
    const unsigned short* __restrict__ w1c_p, const unsigned short* __restrict__ w2_p,
    float* __restrict__ out)
{
    __shared__ __align__(16) unsigned short ldsD[128 * 136];     // 34816 B
    __shared__ __align__(16) unsigned short ldsH1[128 * 264];    // 67584 B
    __shared__ float pp[1024];                                   // 4096 B -> 106496 B

    const int jt = blockIdx.x, ig = blockIdx.y, b = blockIdx.z;
    const int jbase = jt * 128, i0 = ig * NI;
    const int tid = threadIdx.x, wave = tid >> 6, lane = tid & 63;
    const int m0 = lane & 31, q = lane >> 5;
    const int row = tid >> 2, q4 = tid & 3;            // D-build: 4 threads/j-row

    const short8* wcp = (const short8*)w1c_p;
    const short8* w2f = (const short8*)w2_p;
    const float*  pbt = PBT + (size_t)b * 64 * BN * 4;
    const float*  wd  = W1 + (size_t)(3 * EE) * HH;    // w1d row (384)

    // ---- loop-invariant: this thread's j-row slice (32 VGPR, loaded ONCE) ----
    f32x4 jr[8];
    {
        const f32x4* nj = (const f32x4*)(node + ((size_t)b * BN + jbase + row) * EE);
        #pragma unroll
        for (int c = 0; c < 8; ++c) jr[c] = nj[q4 * 8 + c];
    }

    // ---- prologue: build D for i = i0 ----
    {
        const f32x4* hv = (const f32x4*)(node + ((size_t)b * BN + i0) * EE);
        #pragma unroll
        for (int g = 0; g < 4; ++g) {
            f32x4 h0 = hv[q4 * 8 + g * 2], h1v = hv[q4 * 8 + g * 2 + 1];
            short8 pd;
            #pragma unroll
            for (int u = 0; u < 4; ++u) {
                pd[u]     = (short)f2bf(fabsf(jr[g * 2][u]     - h0[u]));
                pd[4 + u] = (short)f2bf(fabsf(jr[g * 2 + 1][u] - h1v[u]));
            }
            *(short8*)&ldsD[row * 136 + q4 * 32 + g * 8] = pd;
        }
    }
    __syncthreads();

    for (int it = 0; it < NI; ++it) {
        const int i = i0 + it;

        // ---- phase A top: issue next i-row + this-iter epi1 inputs early ----
        f32x4 hn[8];
        if (it < NI - 1) {
            const f32x4* hv = (const f32x4*)(node + ((size_t)b * BN + i + 1) * EE);
            #pragma unroll
            for (int c = 0; c < 8; ++c) hn[c] = hv[q4 * 8 + c];
        }
        const float* erow = euclid + ((size_t)b * BN + i) * BN + jbase;
        float ev[4];
        #pragma unroll
        for (int nt = 0; nt < 4; ++nt) ev[nt] = erow[nt * 32 + m0];

        // ---- layer 1: C1^T = W1c^T @ D^T, K=128 (A-frags streamed from L2) ----
        f32x16 C[4];
        #pragma unroll
        for (int nt = 0; nt < 4; ++nt) C[nt] = zero16();
        #pragma unroll
        for (int kb = 0; kb < 8; ++kb) {
            short8 a = wcp[(kb * 8 + wave) * 64 + lane];
            #pragma unroll
            for (int nt = 0; nt < 4; ++nt) {
                short8 bD = *(const short8*)&ldsD[(nt * 32 + m0) * 136 + kb * 16 + q * 8];
                C[nt] = MFMA(a, bD, C[nt]);
            }
        }

        // ---- epi1: h1[pair][f] = relu(C + PA[i][f] + PB[j][f] + e*w1d[f]) ----
        {
            const float* paB = PA + ((size_t)b * BN + i) * HH;
            #pragma unroll
            for (int rg = 0; rg < 4; ++rg) {
                int f0 = wave * 32 + rg * 8;                     // wave-uniform
                f32x4 plo = *(const f32x4*)&paB[f0];
                f32x4 phi = *(const f32x4*)&paB[f0 + 4];
                f32x4 dlo = *(const f32x4*)&wd[f0];
                f32x4 dhi = *(const f32x4*)&wd[f0 + 4];
                #pragma unroll
                for (int nt = 0; nt < 4; ++nt) {
                    f32x4 pbv = *(const f32x4*)&pbt[
                        (((size_t)(f0 >> 2) + q) * BN + jbase + nt * 32 + m0) * 4];
                    short4v w;
                    #pragma unroll
                    for (int u = 0; u < 4; ++u) {
                        float pav = q ? phi[u] : plo[u];
                        float wdv = q ? dhi[u] : dlo[u];
                        float v = C[nt][rg * 4 + u] + pav + pbv[u] + ev[nt] * wdv;
                        v = v > 0.f ? v : 0.f;
                        w[u] = (short)f2bf(v);
                    }
                    *(short4v*)&ldsH1[(nt * 32 + m0) * 264 + f0 + 4 * q] = w;
                }
            }
        }
        __syncthreads();                               // B1: h1 ready, D[cur] dead

        // ---- layer 2: C2^T = W2^T @ h1^T, K=256 (SAME C array: forced sharing) ----
        #pragma unroll
        for (int nt = 0; nt < 4; ++nt) C[nt] = zero16();
        #pragma unroll
        for (int kb = 0; kb < 16; ++kb) {
            short8 a = w2f[(kb * 8 + wave) * 64 + lane];
            #pragma unroll
            for (int nt = 0; nt < 4; ++nt) {
                short8 bh = *(const short8*)&ldsH1[(nt * 32 + m0) * 264 + kb * 16 + q * 8];
                C[nt] = MFMA(a, bh, C[nt]);
            }
        }

        // ---- build D(it+1) (D region dead; overlaps L2's MFMA pipe) ----
        if (it < NI - 1) {
            #pragma unroll
            for (int g = 0; g < 4; ++g) {
                short8 pd;
                #pragma unroll
                for (int u = 0; u < 4; ++u) {
                    pd[u]     = (short)f2bf(fabsf(jr[g * 2][u]     - hn[g * 2][u]));
                    pd[4 + u] = (short)f2bf(fabsf(jr[g * 2 + 1][u] - hn[g * 2 + 1][u]));
                }
                *(short8*)&ldsD[row * 136 + q4 * 32 + g * 8] = pd;
            }
        }

        // ---- layer 3 in registers ----
        {
            float s[4] = {0.f, 0.f, 0.f, 0.f};
            #pragma unroll
            for (int rg = 0; rg < 4; ++rg) {
                int f0 = wave * 32 + rg * 8;                     // wave-uniform
                f32x4 blo = *(const f32x4*)&b2v[f0];
                f32x4 bhi = *(const f32x4*)&b2v[f0 + 4];
                f32x4 wlo = *(const f32x4*)&W3[f0];
                f32x4 whi = *(const f32x4*)&W3[f0 + 4];
                #pragma unroll
                for (int u = 0; u < 4; ++u) {
                    float bb = q ? bhi[u] : blo[u];
                    float ww = q ? whi[u] : wlo[u];
                    #pragma unroll
                    for (int nt = 0; nt < 4; ++nt) {
                        float h2 = C[nt][rg * 4 + u] + bb;
                        h2 = h2 > 0.f ? h2 : 0.f;
                        s[nt] += h2 * ww;
                    }
                }
            }
            #pragma unroll
            for (int nt = 0; nt < 4; ++nt)
                s[nt] += __shfl_xor(s[nt], 32, 64);   // fold q-halves
            if (lane < 32) {
                #pragma unroll
                for (int nt = 0; nt < 4; ++nt)
                    pp[wave * 128 + nt * 32 + lane] = s[nt];
            }
        }
        __syncthreads();                               // B2: pp + D[next] ready
        if (tid < 128) {
            float v = b3[0];
            #pragma unroll
            for (int w8 = 0; w8 < 8; ++w8) v += pp[w8 * 128 + tid];
            out[((size_t)b * BN + i) * BN + jbase + tid] = v;
        }
    }
}

// ---------------- kernel 2: in-place symmetrize + zero diagonal ----------------
__global__ void symmetrize(float* __restrict__ out) {
    int b = blockIdx.z, ti = blockIdx.y, tj = blockIdx.x;
    if (tj < ti) return;
    int i = ti * 32 + threadIdx.y, j = tj * 32 + threadIdx.x;
    float* p = out + (size_t)b * BN * BN;
    if (i == j) { p[(size_t)i * BN + j] = 0.f; return; }
    if (j < i) return;
    float a = p[(size_t)i * BN + j];
    float c = p[(size_t)j * BN + i];
    float v = 0.5f * (a + c);
    p[(size_t)i * BN + j] = v;
    p[(size_t)j * BN + i] = v;
}

extern "C" void kernel_launch(void* const* d_in, const int* in_sizes, int n_in,
                              void* d_out, int out_size, void* d_ws, size_t ws_size,
                              hipStream_t stream) {
    const float* node   = (const float*)d_in[0];
    const float* euclid = (const float*)d_in[2];
    const float* W1     = (const float*)d_in[3];
    const float* b1     = (const float*)d_in[4];
    const float* W2     = (const float*)d_in[5];
    const float* b2     = (const float*)d_in[6];
    const float* W3     = (const float*)d_in[7];
    const float* b3     = (const float*)d_in[8];
    float* out = (float*)d_out;

    char* ws = (char*)d_ws;
    float*          PA    = (float*)ws;                                   // 1 MB
    float*          PBT   = (float*)(ws + (1u << 20));                    // 1 MB
    unsigned short* w1c_p = (unsigned short*)(ws + (2u << 20));           // 64 KB
    unsigned short* w2_p  = (unsigned short*)(ws + (2u << 20) + 65536);   // 128 KB

    prep<<<512, 256, 0, stream>>>(node, W1, W2, b1, PA, PBT, w1c_p, w2_p);
    edge_main<<<dim3(4, BN / NI, 2), 512, 0, stream>>>(
        node, euclid, W1, W3, b3, b2, PA, PBT, w1c_p, w2_p, out);
    symmetrize<<<dim3(BN / 32, BN / 32, 2), dim3(32, 32), 0, stream>>>(out);
}